// Round 5
// baseline (216.994 us; speedup 1.0000x reference)
//
#include <hip/hip_runtime.h>
#include <math.h>

typedef unsigned long long ull;
typedef unsigned int uint;

#define NBOX 21840
#define SEGSZ 512
#define NSEG 44
#define NPAD (NSEG*SEGSZ)     // 22528
#define PFXS 46               // staged per segment
#define OUTW 47               // 46 staged + 1 pref key
#define NWALK (NSEG*PFXS)     // 2024
#define MCAP 2048
#define MTX 512               // suppression-matrix window
#define BATCH 32
#define NCLS 21
#define NEGV -1e30f
// midpoint(0.45f, nextafterf(0.45f)) = 15099494.5 * 2^-25, exactly representable.
// RN(inter/u) > 0.45f  <=>  (double)inter > MIOU * (double)u   (u > 0)
#define MIOU (15099494.5/33554432.0)

// ---- sortable key: ascending u64 == (score desc, idx asc); lo = (idx<<8)|cls ----
__device__ __forceinline__ uint key_hi(float s) {
    uint b = __float_as_uint(s);
    uint m = (uint)((int)b >> 31) | 0x80000000u;
    return ~(b ^ m);                       // valid (s>0.01>0) => hi < 0x80000000
}
__device__ __forceinline__ float key_score(uint hi) {
    uint srt = ~hi;
    uint b = (srt & 0x80000000u) ? (srt ^ 0x80000000u) : ~srt;
    return __uint_as_float(b);
}

__device__ __forceinline__ float area_of(float4 b) {
    return __fmul_rn(__fsub_rn(b.z, b.x), __fsub_rn(b.w, b.y));
}
// exact iou>0.45 decision, divide-free (strict > at midpoint; tie rounds to even=0.45f)
__device__ __forceinline__ bool sup_check(float4 a, float aarea, float4 c, float carea) {
    float ix1 = fmaxf(a.x, c.x), iy1 = fmaxf(a.y, c.y);
    float ix2 = fminf(a.z, c.z), iy2 = fminf(a.w, c.w);
    float inter = __fmul_rn(fmaxf(__fsub_rn(ix2, ix1), 0.f), fmaxf(__fsub_rn(iy2, iy1), 0.f));
    float uni = __fsub_rn(__fadd_rn(aarea, carea), inter);
    return (uni > 0.f) && ((double)inter > MIOU * (double)fmaxf(uni, 1e-12f));
}

// one bitonic compare-exchange pass with j<=32: partner is in-wave, via shfl
__device__ __forceinline__ ull cex_shfl(ull v, int j, bool asc, int lane) {
    ull pv = __shfl_xor(v, j);
    bool keepmin = (((lane & j) == 0) == asc);
    bool less = (v < pv);
    return (keepmin == less) ? v : pv;
}

// ---------------- Kernel A: fused decode + per-segment sort (512 boxes/block) ----------------
__global__ __launch_bounds__(512) void decode_sort_kernel(
    const float* __restrict__ y_pred, const float* __restrict__ box_tensor,
    float4* __restrict__ BX, ull* __restrict__ KS, ull* __restrict__ KS2)
{
    __shared__ float st[SEGSZ * 25];   // 51.2 KB
    __shared__ ull sk[SEGSZ];          // 4 KB
    int img = blockIdx.y, seg = blockIdx.x, tid = threadIdx.x;
    int b0 = seg * SEGSZ;
    int nval = NBOX - b0; nval = nval < 0 ? 0 : (nval > SEGSZ ? SEGSZ : nval);
    if (nval > 0) {
        const float* src = y_pred + ((size_t)img * NBOX + b0) * 25;
        int nf = nval * 25, nf4 = nf >> 2;
        const float4* src4 = (const float4*)src;
        float4* st4 = (float4*)st;
        for (int f = tid; f < nf4; f += 512) st4[f] = src4[f];
        for (int f = (nf4 << 2) + tid; f < nf; f += 512) st[f] = src[f];
    }
    __syncthreads();
    int i = b0 + tid;
    size_t o = (size_t)img * NPAD + i;
    ull v;
    if (tid < nval) {
        const float* yl = st + tid * 25;
        float best = yl[0]; int bi = 0;
        #pragma unroll
        for (int k = 1; k < NCLS; k++) { float x = yl[k]; if (x > best) { best = x; bi = k; } }
        float4 a = ((const float4*)box_tensor)[i];
        float t0 = yl[21], t1 = yl[22], t2 = yl[23], t3 = yl[24];
        float cx = __fadd_rn(__fmul_rn(__fmul_rn(t0, 0.1f), a.z), a.x);
        float cy = __fadd_rn(__fmul_rn(__fmul_rn(t1, 0.1f), a.w), a.y);
        float w  = __fmul_rn((float)exp((double)__fmul_rn(t2, 0.2f)), a.z);
        float h  = __fmul_rn((float)exp((double)__fmul_rn(t3, 0.2f)), a.w);
        float hw = __fmul_rn(0.5f, w), hh = __fmul_rn(0.5f, h);
        float xmin = fminf(fmaxf(__fsub_rn(cx, hw), 0.f), 1.f);
        float ymin = fminf(fmaxf(__fsub_rn(cy, hh), 0.f), 1.f);
        float xmax = fminf(fmaxf(__fadd_rn(cx, hw), 0.f), 1.f);
        float ymax = fminf(fmaxf(__fadd_rn(cy, hh), 0.f), 1.f);
        bool valid = (bi != 0) && (best > 0.01f);
        BX[o] = make_float4(xmin, ymin, xmax, ymax);
        uint hi = valid ? key_hi(best) : __float_as_uint(NEGV);
        v = ((ull)hi << 32) | ((uint)(i << 8)) | (uint)bi;
    } else {
        v = ((ull)__float_as_uint(NEGV) << 32) | ((uint)(i << 8));
    }
    // hybrid bitonic sort of 512 keys: j>=64 via LDS, j<=32 via shfl
    int lane = tid & 63;
    for (int k = 2; k <= SEGSZ; k <<= 1) {
        for (int j = k >> 1; j >= 64; j >>= 1) {
            sk[tid] = v; __syncthreads();
            ull pv = sk[tid ^ j];
            bool keepmin = (((tid & j) == 0) == ((tid & k) == 0));
            bool less = (v < pv);
            v = (keepmin == less) ? v : pv;
            __syncthreads();
        }
        int j0 = (k >> 1) < 32 ? (k >> 1) : 32;
        for (int j = j0; j >= 1; j >>= 1)
            v = cex_shfl(v, j, (tid & k) == 0, lane);
    }
    KS[(size_t)img * NPAD + b0 + tid] = v;                              // sorted segment (fallback)
    if (tid < OUTW) KS2[(size_t)img * (NSEG * OUTW) + seg * OUTW + tid] = v;
}

// ---------------- Kernel B: merge + suppression-matrix + bit-resolve NMS ----------------
__global__ __launch_bounds__(512) void nms_kernel(
    const ull* __restrict__ KS2, const ull* __restrict__ KS,
    const float4* __restrict__ BX, float* __restrict__ out)
{
    __shared__ ull klist[MCAP];          // 16 KB
    __shared__ ull rows[MTX][8];         // 32 KB
    __shared__ float4 cbox[MTX];         // 8 KB
    __shared__ float4 accbox[100];
    __shared__ ull pref[NSEG];
    __shared__ int limsh;

    int img = blockIdx.x, tid = threadIdx.x;
    int wid = tid >> 6, lane = tid & 63;
    const ull* ks2i = KS2 + (size_t)img * (NSEG * OUTW);
    const float4* BXg = BX + (size_t)img * NPAD;

    if (tid == 0) limsh = 0;

    // stage 44 sorted prefixes of 46 into registers
    ull v[4];
    #pragma unroll
    for (int r = 0; r < 4; r++) {
        int e = (wid << 8) + (r << 6) + lane;
        v[r] = (e < NWALK) ? ks2i[(e / PFXS) * OUTW + (e % PFXS)] : ~0ull;
    }
    if (tid < NSEG) pref[tid] = ks2i[tid * OUTW + PFXS];

    // hybrid bitonic sort 2048 ascending
    for (int k = 2; k <= MCAP; k <<= 1) {
        int jl = k >> 1;
        if (jl >= 64) {
            #pragma unroll
            for (int r = 0; r < 4; r++) klist[(wid << 8) + (r << 6) + lane] = v[r];
            for (int j = jl; j >= 64; j >>= 1) {
                __syncthreads();
                for (int t = tid; t < MCAP / 2; t += 512) {
                    int i = ((t & ~(j - 1)) << 1) | (t & (j - 1));
                    int l = i | j;
                    ull a = klist[i], b = klist[l];
                    if ((a > b) == ((i & k) == 0)) { klist[i] = b; klist[l] = a; }
                }
            }
            __syncthreads();
            #pragma unroll
            for (int r = 0; r < 4; r++) v[r] = klist[(wid << 8) + (r << 6) + lane];
        }
        int j0 = jl < 32 ? jl : 32;
        for (int j = j0; j >= 1; j >>= 1) {
            #pragma unroll
            for (int r = 0; r < 4; r++) {
                int e = (wid << 8) + (r << 6) + lane;
                v[r] = cex_shfl(v[r], j, (e & k) == 0, lane);
            }
        }
    }
    #pragma unroll
    for (int r = 0; r < 4; r++) klist[(wid << 8) + (r << 6) + lane] = v[r];

    // cutk = min over segments of first un-staged key; lim = #keys strictly below min(cutk, NEG)
    ull cutk = ~0ull;
    for (int s = 0; s < NSEG; s++) { ull x = pref[s]; if (x < cutk) cutk = x; }
    ull limk = (cutk < (1ull << 63)) ? cutk : (1ull << 63);
    int cnt = 0;
    #pragma unroll
    for (int r = 0; r < 4; r++) cnt += __popcll(__ballot(v[r] < limk));
    if (lane == 0) atomicAdd(&limsh, cnt);
    __syncthreads();
    int lim = limsh;

    // gather candidate boxes for the matrix window
    {
        ull k = klist[tid];
        cbox[tid] = (k >> 63) ? make_float4(9.f, 9.f, 9.f, 9.f) : BXg[((uint)k) >> 8];
    }
    __syncthreads();

    // suppression matrix (triangular): wave 'wid' handles rows wid, wid+8, ...
    for (int r = wid; r < MTX; r += 8) {
        float4 rb = cbox[r];
        float ra = area_of(rb);
        int w0 = r >> 6;
        ull myword = 0;
        #pragma unroll
        for (int wi = 0; wi < 8; wi++) {
            ull m = 0;
            if (wi >= w0) {
                int j = (wi << 6) + lane;
                float4 jb = cbox[j];
                bool s = (j > r) && sup_check(rb, ra, jb, area_of(jb));
                m = __ballot(s);
            }
            if (lane == wi) myword = m;
        }
        if (lane < 8) rows[r][lane] = myword;
    }
    __syncthreads();

    if (tid >= 64) return;             // resolve: wave 0 only (no more block syncs)
    float* orow = out + (size_t)img * 600;
    const ull* ksg = KS + (size_t)img * NPAD;

    // phase A: pure bitmask greedy resolve over the matrix window
    ull S[8];
    #pragma unroll
    for (int w = 0; w < 8; w++) S[w] = 0;
    int lim512 = lim < MTX ? lim : MTX;
    int A = 0;
    int acc0 = 0, acc1 = 0;            // accepted positions: slot=lane (acc0), slot=64+lane (acc1)

    for (;;) {
        int c = MTX;
        #pragma unroll
        for (int w = 7; w >= 0; w--) {
            ull m = ~S[w];
            if (m) c = (w << 6) + __ffsll(m) - 1;
        }
        if (c >= lim512) break;
        #pragma unroll
        for (int w = 0; w < 8; w++) {      // OR accepted row + self-bit
            ull rr = rows[c][w];
            if (w == (c >> 6)) rr |= 1ull << (c & 63);
            S[w] |= rr;
        }
        if (lane == (A & 63)) { if (A < 64) acc0 = c; else acc1 = c; }
        A++;
        if (A >= 100) break;
    }
    int accA = A;

    // batch-write phase-A outputs (lane-parallel)
    if (lane < accA) {
        int c = acc0; ull k = klist[c]; float4 b = cbox[c];
        float* o = orow + lane * 6;
        o[0] = (float)((uint)k & 0xffu); o[1] = key_score((uint)(k >> 32));
        o[2] = b.x; o[3] = b.y; o[4] = b.z; o[5] = b.w;
    }
    if (64 + lane < accA) {
        int c = acc1; ull k = klist[c]; float4 b = cbox[c];
        float* o = orow + (64 + lane) * 6;
        o[0] = (float)((uint)k & 0xffu); o[1] = key_score((uint)(k >> 32));
        o[2] = b.x; o[3] = b.y; o[4] = b.z; o[5] = b.w;
    }

    int done = 1;
    if (A < 100) {
        // rebuild accepted-box list for continuation phases
        if (lane < A)      accbox[lane]      = cbox[acc0];
        if (64 + lane < A) accbox[64 + lane] = cbox[acc1];
        done = 0;
        if (lim <= MTX) {
            done = (int)(cutk >> 63);      // all valid staged keys processed iff cutk is NEG
        } else {
            // phase B: staged keys beyond the matrix window, exact order up to lim
            int stop = 0;
            for (int base = MTX; base < MCAP && !stop; base += 64) {
                int pos = base + lane;
                ull kk = klist[pos];
                bool valid = pos < lim;
                ull vmask = __ballot(valid);
                float4 bb = (kk >> 63) ? make_float4(9.f,9.f,9.f,9.f) : BXg[((uint)kk) >> 8];
                float ca = area_of(bb);
                bool pr = false;
                for (int a = 0; a < A; a++) {
                    float4 ab = accbox[a];
                    pr = pr || sup_check(ab, area_of(ab), bb, ca);
                }
                ull cand = __ballot(valid && !pr);
                while (cand && A < 100) {
                    int i = __ffsll(cand) - 1;
                    float4 ib = make_float4(__shfl(bb.x, i), __shfl(bb.y, i),
                                            __shfl(bb.z, i), __shfl(bb.w, i));
                    float ia = __shfl(ca, i);
                    ull row = __ballot(sup_check(ib, ia, bb, ca));
                    if (lane == i) {
                        accbox[A] = bb;
                        float* o = orow + A * 6;
                        o[0] = (float)((uint)kk & 0xffu); o[1] = key_score((uint)(kk >> 32));
                        o[2] = bb.x; o[3] = bb.y; o[4] = bb.z; o[5] = bb.w;
                    }
                    A++;
                    cand &= ~(1ull << i);
                    cand &= ~row;
                }
                if (A >= 100) { stop = 1; done = 1; }
                else if (vmask != ~0ull) { stop = 1; done = (int)(cutk >> 63); }
                __builtin_amdgcn_wave_barrier();
            }
            if (!stop) done = (int)(cutk >> 63);
        }
        // phase C fallback (expected dead): ordered pops over full key array from cutk
        if (!done && A < 100) {
            ull nextk = cutk;
            while (A < 100) {
                ull best = ~0ull;
                for (int e = lane; e < NPAD; e += 64) {
                    ull kk2 = ksg[e];
                    if (kk2 >= nextk && kk2 < best) best = kk2;
                }
                #pragma unroll
                for (int off = 32; off; off >>= 1) {
                    ull oo = __shfl_xor(best, off);
                    if (oo < best) best = oo;
                }
                if (best >> 63) break;
                uint bhi = (uint)(best >> 32), blo = (uint)best;
                float4 cb = BXg[blo >> 8];
                float ca2 = area_of(cb);
                bool sup2 = false;
                #pragma unroll
                for (int t = 0; t < 2; t++) {
                    int slot = lane + 64 * t;
                    if (slot < A) {
                        float4 ab = accbox[slot];
                        if (sup_check(ab, area_of(ab), cb, ca2)) sup2 = true;
                    }
                }
                if (__ballot(sup2) == 0ull) {
                    if (lane == 0) {
                        accbox[A] = cb;
                        float* o = orow + A * 6;
                        o[0] = (float)(blo & 0xffu); o[1] = key_score(bhi);
                        o[2] = cb.x; o[3] = cb.y; o[4] = cb.z; o[5] = cb.w;
                    }
                    A++;
                }
                nextk = best + 1;
                __builtin_amdgcn_wave_barrier();
            }
        }
    }

    for (int r = lane; r < (100 - A) * 6; r += 64) orow[A * 6 + r] = 0.f;
}

extern "C" void kernel_launch(void* const* d_in, const int* in_sizes, int n_in,
                              void* d_out, int out_size, void* d_ws, size_t ws_size,
                              hipStream_t stream)
{
    const float* y_pred     = (const float*)d_in[0];
    const float* box_tensor = (const float*)d_in[1];
    float* out = (float*)d_out;

    size_t stride = (size_t)BATCH * NPAD;
    ull*    KS  = (ull*)d_ws;                       // 5.77 MB
    float4* BX  = (float4*)(KS + stride);           // 11.53 MB
    ull*    KS2 = (ull*)(BX + stride);              // 0.53 MB

    decode_sort_kernel<<<dim3(NSEG, BATCH), 512, 0, stream>>>(y_pred, box_tensor, BX, KS, KS2);
    nms_kernel<<<BATCH, 512, 0, stream>>>(KS2, KS, BX, out);
}

// Round 6
// 161.012 us; speedup vs baseline: 1.3477x; 1.3477x over previous
//
#include <hip/hip_runtime.h>
#include <math.h>

typedef unsigned long long ull;
typedef unsigned int uint;

#define NBOX 21840
#define SEGSZ 512
#define NSEG 44
#define NPAD (NSEG*SEGSZ)     // 22528
#define PFXS 46               // staged per segment
#define OUTW 47               // 46 staged + 1 pref key
#define NWALK (NSEG*PFXS)     // 2024
#define MCAP 2048
#define WIN 1024              // fast window with precomputed within-batch masks
#define BATCH 32
#define NCLS 21
#define NEGV -1e30f
// midpoint(0.45f, nextafterf(0.45f)) = 15099494.5 * 2^-25, exactly representable.
// RN(inter/u) > 0.45f  <=>  (double)inter > MIOU * (double)u   (u > 0)
#define MIOU (15099494.5/33554432.0)

// ---- sortable key: ascending u64 == (score desc, idx asc); lo = (idx<<8)|cls ----
__device__ __forceinline__ uint key_hi(float s) {
    uint b = __float_as_uint(s);
    uint m = (uint)((int)b >> 31) | 0x80000000u;
    return ~(b ^ m);                       // valid (s>0.01>0) => hi < 0x80000000
}
__device__ __forceinline__ float key_score(uint hi) {
    uint srt = ~hi;
    uint b = (srt & 0x80000000u) ? (srt ^ 0x80000000u) : ~srt;
    return __uint_as_float(b);
}

__device__ __forceinline__ float area_of(float4 b) {
    return __fmul_rn(__fsub_rn(b.z, b.x), __fsub_rn(b.w, b.y));
}
// exact iou>0.45 decision, divide-free (strict > at midpoint; tie rounds to even=0.45f)
__device__ __forceinline__ bool sup_check(float4 a, float aarea, float4 c, float carea) {
    float ix1 = fmaxf(a.x, c.x), iy1 = fmaxf(a.y, c.y);
    float ix2 = fminf(a.z, c.z), iy2 = fminf(a.w, c.w);
    float inter = __fmul_rn(fmaxf(__fsub_rn(ix2, ix1), 0.f), fmaxf(__fsub_rn(iy2, iy1), 0.f));
    float uni = __fsub_rn(__fadd_rn(aarea, carea), inter);
    return (uni > 0.f) && ((double)inter > MIOU * (double)fmaxf(uni, 1e-12f));
}

// one bitonic compare-exchange pass with j<=32: partner is in-wave, via shfl
__device__ __forceinline__ ull cex_shfl(ull v, int j, bool asc, int lane) {
    ull pv = __shfl_xor(v, j);
    bool keepmin = (((lane & j) == 0) == asc);
    bool less = (v < pv);
    return (keepmin == less) ? v : pv;
}

// ---------------- Kernel A: fused decode + per-segment sort (512 boxes/block) ----------------
__global__ __launch_bounds__(512) void decode_sort_kernel(
    const float* __restrict__ y_pred, const float* __restrict__ box_tensor,
    float4* __restrict__ BX, ull* __restrict__ KS, ull* __restrict__ KS2)
{
    __shared__ float st[SEGSZ * 25];   // 51.2 KB
    __shared__ ull sk[SEGSZ];          // 4 KB
    int img = blockIdx.y, seg = blockIdx.x, tid = threadIdx.x;
    int b0 = seg * SEGSZ;
    int nval = NBOX - b0; nval = nval < 0 ? 0 : (nval > SEGSZ ? SEGSZ : nval);
    if (nval > 0) {
        const float* src = y_pred + ((size_t)img * NBOX + b0) * 25;
        int nf = nval * 25, nf4 = nf >> 2;
        const float4* src4 = (const float4*)src;
        float4* st4 = (float4*)st;
        for (int f = tid; f < nf4; f += 512) st4[f] = src4[f];
        for (int f = (nf4 << 2) + tid; f < nf; f += 512) st[f] = src[f];
    }
    __syncthreads();
    int i = b0 + tid;
    size_t o = (size_t)img * NPAD + i;
    ull v;
    if (tid < nval) {
        const float* yl = st + tid * 25;
        float best = yl[0]; int bi = 0;
        #pragma unroll
        for (int k = 1; k < NCLS; k++) { float x = yl[k]; if (x > best) { best = x; bi = k; } }
        float4 a = ((const float4*)box_tensor)[i];
        float t0 = yl[21], t1 = yl[22], t2 = yl[23], t3 = yl[24];
        float cx = __fadd_rn(__fmul_rn(__fmul_rn(t0, 0.1f), a.z), a.x);
        float cy = __fadd_rn(__fmul_rn(__fmul_rn(t1, 0.1f), a.w), a.y);
        float w  = __fmul_rn((float)exp((double)__fmul_rn(t2, 0.2f)), a.z);
        float h  = __fmul_rn((float)exp((double)__fmul_rn(t3, 0.2f)), a.w);
        float hw = __fmul_rn(0.5f, w), hh = __fmul_rn(0.5f, h);
        float xmin = fminf(fmaxf(__fsub_rn(cx, hw), 0.f), 1.f);
        float ymin = fminf(fmaxf(__fsub_rn(cy, hh), 0.f), 1.f);
        float xmax = fminf(fmaxf(__fadd_rn(cx, hw), 0.f), 1.f);
        float ymax = fminf(fmaxf(__fadd_rn(cy, hh), 0.f), 1.f);
        bool valid = (bi != 0) && (best > 0.01f);
        BX[o] = make_float4(xmin, ymin, xmax, ymax);
        uint hi = valid ? key_hi(best) : __float_as_uint(NEGV);
        v = ((ull)hi << 32) | ((uint)(i << 8)) | (uint)bi;
    } else {
        v = ((ull)__float_as_uint(NEGV) << 32) | ((uint)(i << 8));
    }
    // hybrid bitonic sort of 512 keys: j>=64 via LDS, j<=32 via shfl
    int lane = tid & 63;
    for (int k = 2; k <= SEGSZ; k <<= 1) {
        for (int j = k >> 1; j >= 64; j >>= 1) {
            sk[tid] = v; __syncthreads();
            ull pv = sk[tid ^ j];
            bool keepmin = (((tid & j) == 0) == ((tid & k) == 0));
            bool less = (v < pv);
            v = (keepmin == less) ? v : pv;
            __syncthreads();
        }
        int j0 = (k >> 1) < 32 ? (k >> 1) : 32;
        for (int j = j0; j >= 1; j >>= 1)
            v = cex_shfl(v, j, (tid & k) == 0, lane);
    }
    KS[(size_t)img * NPAD + b0 + tid] = v;                              // sorted segment (fallback)
    if (tid < OUTW) KS2[(size_t)img * (NSEG * OUTW) + seg * OUTW + tid] = v;
}

// ---------------- Kernel B: merge + batched greedy walk w/ precomputed in-batch masks ----------------
__global__ __launch_bounds__(512) void nms_kernel(
    const ull* __restrict__ KS2, const ull* __restrict__ KS,
    const float4* __restrict__ BX, float* __restrict__ out)
{
    __shared__ ull klist[MCAP];        // 16 KB
    __shared__ float4 cbox[WIN];       // 16 KB
    __shared__ ull scol[WIN];          // 8 KB  (bit i of scol[c]: batch-mate i suppresses c)
    __shared__ float4 accbox[100];
    __shared__ float  accarea[100];
    __shared__ ull pref[NSEG];

    int img = blockIdx.x, tid = threadIdx.x;
    int wid = tid >> 6, lane = tid & 63;
    const ull* ks2i = KS2 + (size_t)img * (NSEG * OUTW);
    const float4* BXg = BX + (size_t)img * NPAD;

    // stage 44 sorted prefixes of 46 into registers; e = wid*256 + r*64 + lane
    ull v[4];
    #pragma unroll
    for (int r = 0; r < 4; r++) {
        int e = (wid << 8) + (r << 6) + lane;
        v[r] = (e < NWALK) ? ks2i[(e / PFXS) * OUTW + (e % PFXS)] : ~0ull;
    }
    if (tid < NSEG) pref[tid] = ks2i[tid * OUTW + PFXS];

    // hybrid bitonic sort 2048 ascending: LDS (j>=256), reg (j=128,64), shfl (j<=32)
    for (int k = 2; k <= MCAP; k <<= 1) {
        if ((k >> 1) >= 256) {
            #pragma unroll
            for (int r = 0; r < 4; r++) klist[(wid << 8) + (r << 6) + lane] = v[r];
            for (int j = k >> 1; j >= 256; j >>= 1) {
                __syncthreads();
                #pragma unroll
                for (int h = 0; h < 2; h++) {
                    int t = tid + (h << 9);
                    int i = ((t & ~(j - 1)) << 1) | (t & (j - 1));
                    int l = i | j;
                    ull a = klist[i], b = klist[l];
                    if ((a > b) == ((i & k) == 0)) { klist[i] = b; klist[l] = a; }
                }
            }
            __syncthreads();
            #pragma unroll
            for (int r = 0; r < 4; r++) v[r] = klist[(wid << 8) + (r << 6) + lane];
        }
        #pragma unroll
        for (int jr = 2; jr >= 1; jr >>= 1) {          // j = 128, 64: same-lane register CE
            int j = jr << 6;
            if ((k >> 1) >= j) {
                #pragma unroll
                for (int r = 0; r < 4; r++) {
                    if ((r & jr) == 0) {
                        int rh = r | jr;
                        int e = (wid << 8) + (r << 6) + lane;
                        bool asc = ((e & k) == 0);
                        ull a = v[r], b = v[rh];
                        if ((a > b) == asc) { v[r] = b; v[rh] = a; }
                    }
                }
            }
        }
        int j0 = (k >> 1) < 32 ? (k >> 1) : 32;
        for (int j = j0; j >= 1; j >>= 1) {
            #pragma unroll
            for (int r = 0; r < 4; r++) {
                int e = (wid << 8) + (r << 6) + lane;
                v[r] = cex_shfl(v[r], j, (e & k) == 0, lane);
            }
        }
    }
    #pragma unroll
    for (int r = 0; r < 4; r++) klist[(wid << 8) + (r << 6) + lane] = v[r];
    __syncthreads();

    // window prep: all 8 waves gather boxes + within-batch suppressor columns
    for (int b = wid; b < (WIN >> 6); b += 8) {
        int c = (b << 6) + lane;
        ull k = klist[c];
        float4 bx = BXg[((uint)k) >> 8];
        cbox[c] = bx;
        float myar = area_of(bx);
        ull col = 0;
        #pragma unroll 4
        for (int i = 0; i < 64; i++) {
            float4 ib = cbox[(b << 6) + i];
            bool s = (i < lane) && sup_check(ib, area_of(ib), bx, myar);
            col |= ((ull)s) << i;
        }
        scol[c] = col;
    }
    __syncthreads();

    if (tid >= 64) return;             // resolve: wave 0 only
    float* orow = out + (size_t)img * 600;
    const ull* ksg = KS + (size_t)img * NPAD;

    ull cutk = ~0ull;
    for (int s = 0; s < NSEG; s++) { ull x = pref[s]; if (x < cutk) cutk = x; }

    int A = 0, stop = 0, done = 0;
    int acc0 = 0, acc1 = 0;            // accepted window positions per lane

    for (int base = 0; base < WIN && !stop; base += 64) {
        int c = base + lane;
        ull kk = klist[c];
        float4 bb = cbox[c];
        float ca = area_of(bb);
        ull mycol = scol[c];
        bool valid = !(kk >> 63) && (kk < cutk);
        ull vmask = __ballot(valid);
        bool alive = valid;
        for (int a = 0; a < A; a++)
            alive = alive && !sup_check(accbox[a], accarea[a], bb, ca);
        ull m = __ballot(alive);
        while (m && A < 100) {
            int i = __ffsll(m) - 1;
            if (lane == i) { accbox[A] = bb; accarea[A] = ca; }
            if (lane == (A & 63)) { if (A < 64) acc0 = base + i; else acc1 = base + i; }
            A++;
            m &= ~(1ull << i);
            m &= __ballot(!((mycol >> i) & 1ull));
        }
        if (A >= 100) { stop = 1; done = 1; }
        else if (vmask != ~0ull) {
            stop = 1;
            int fi = __ffsll(~vmask) - 1;
            ull fk = __shfl(kk, fi);
            done = (fk >= cutk) ? (int)(cutk >> 63) : 1;
        }
        __builtin_amdgcn_wave_barrier();
    }

    // batch-write window outputs (lane-parallel)
    int accW = A;
    if (lane < accW) {
        ull k = klist[acc0]; float4 b = cbox[acc0];
        float* o = orow + lane * 6;
        o[0] = (float)((uint)k & 0xffu); o[1] = key_score((uint)(k >> 32));
        o[2] = b.x; o[3] = b.y; o[4] = b.z; o[5] = b.w;
    }
    if (64 + lane < accW) {
        ull k = klist[acc1]; float4 b = cbox[acc1];
        float* o = orow + (64 + lane) * 6;
        o[0] = (float)((uint)k & 0xffu); o[1] = key_score((uint)(k >> 32));
        o[2] = b.x; o[3] = b.y; o[4] = b.z; o[5] = b.w;
    }

    // slow continuation beyond the window (expected dead: walk depth ~435 < WIN)
    if (!stop) {
        for (int base = WIN; base < MCAP && !stop; base += 64) {
            int pos = base + lane;
            ull kk = klist[pos];
            bool valid = !(kk >> 63) && (kk < cutk);
            ull vmask = __ballot(valid);
            float4 bb = BXg[((uint)kk) >> 8];
            float ca = area_of(bb);
            bool alive = valid;
            for (int a = 0; a < A; a++)
                alive = alive && !sup_check(accbox[a], accarea[a], bb, ca);
            ull cand = __ballot(alive);
            while (cand && A < 100) {
                int i = __ffsll(cand) - 1;
                float4 ib = make_float4(__shfl(bb.x, i), __shfl(bb.y, i),
                                        __shfl(bb.z, i), __shfl(bb.w, i));
                float ia = __shfl(ca, i);
                ull row = __ballot(sup_check(ib, ia, bb, ca));
                if (lane == i) {
                    accbox[A] = bb; accarea[A] = ca;
                    float* o = orow + A * 6;
                    o[0] = (float)((uint)kk & 0xffu); o[1] = key_score((uint)(kk >> 32));
                    o[2] = bb.x; o[3] = bb.y; o[4] = bb.z; o[5] = bb.w;
                }
                A++;
                cand &= ~(1ull << i);
                cand &= ~row;
            }
            if (A >= 100) { stop = 1; done = 1; }
            else if (vmask != ~0ull) {
                stop = 1;
                int fi = __ffsll(~vmask) - 1;
                ull fk = __shfl(kk, fi);
                done = (fk >= cutk) ? (int)(cutk >> 63) : 1;
            }
            __builtin_amdgcn_wave_barrier();
        }
        if (!stop) done = (int)(cutk >> 63);
    }

    // phase C fallback (expected dead): ordered pops over full key array from cutk
    if (!done && A < 100) {
        ull nextk = cutk;
        while (A < 100) {
            ull best = ~0ull;
            for (int e = lane; e < NPAD; e += 64) {
                ull kk2 = ksg[e];
                if (kk2 >= nextk && kk2 < best) best = kk2;
            }
            #pragma unroll
            for (int off = 32; off; off >>= 1) {
                ull oo = __shfl_xor(best, off);
                if (oo < best) best = oo;
            }
            if (best >> 63) break;
            uint bhi = (uint)(best >> 32), blo = (uint)best;
            float4 cb = BXg[blo >> 8];
            float ca2 = area_of(cb);
            bool sup2 = false;
            #pragma unroll
            for (int t = 0; t < 2; t++) {
                int slot = lane + 64 * t;
                if (slot < A && sup_check(accbox[slot], accarea[slot], cb, ca2)) sup2 = true;
            }
            if (__ballot(sup2) == 0ull) {
                if (lane == 0) {
                    accbox[A] = cb; accarea[A] = ca2;
                    float* o = orow + A * 6;
                    o[0] = (float)(blo & 0xffu); o[1] = key_score(bhi);
                    o[2] = cb.x; o[3] = cb.y; o[4] = cb.z; o[5] = cb.w;
                }
                A++;
            }
            nextk = best + 1;
            __builtin_amdgcn_wave_barrier();
        }
    }

    for (int r = lane; r < (100 - A) * 6; r += 64) orow[A * 6 + r] = 0.f;
}

extern "C" void kernel_launch(void* const* d_in, const int* in_sizes, int n_in,
                              void* d_out, int out_size, void* d_ws, size_t ws_size,
                              hipStream_t stream)
{
    const float* y_pred     = (const float*)d_in[0];
    const float* box_tensor = (const float*)d_in[1];
    float* out = (float*)d_out;

    size_t stride = (size_t)BATCH * NPAD;
    ull*    KS  = (ull*)d_ws;                       // 5.77 MB
    float4* BX  = (float4*)(KS + stride);           // 11.53 MB
    ull*    KS2 = (ull*)(BX + stride);              // 0.53 MB

    decode_sort_kernel<<<dim3(NSEG, BATCH), 512, 0, stream>>>(y_pred, box_tensor, BX, KS, KS2);
    nms_kernel<<<BATCH, 512, 0, stream>>>(KS2, KS, BX, out);
}

// Round 7
// 143.509 us; speedup vs baseline: 1.5121x; 1.1220x over previous
//
#include <hip/hip_runtime.h>
#include <math.h>

typedef unsigned long long ull;
typedef unsigned int uint;

#define NBOX 21840
#define SEGSZ 512
#define NSEG 44
#define NPAD (NSEG*SEGSZ)     // 22528
#define PFXS 23               // staged per segment
#define OUTW 24               // 23 staged + 1 pref key
#define NWALK (NSEG*PFXS)     // 1012
#define MCAP 1024
#define WIN 512               // fast window with precomputed within-batch masks
#define BATCH 32
#define NCLS 21
#define NEGV -1e30f
// midpoint(0.45f, nextafterf(0.45f)) = 15099494.5 * 2^-25, exactly representable.
// RN(inter/u) > 0.45f  <=>  (double)inter > MIOU * (double)u   (u > 0)
#define MIOU (15099494.5/33554432.0)

// ---- sortable key: ascending u64 == (score desc, idx asc); lo = (idx<<8)|cls ----
__device__ __forceinline__ uint key_hi(float s) {
    uint b = __float_as_uint(s);
    uint m = (uint)((int)b >> 31) | 0x80000000u;
    return ~(b ^ m);                       // valid (s>0.01>0) => hi < 0x80000000
}
__device__ __forceinline__ float key_score(uint hi) {
    uint srt = ~hi;
    uint b = (srt & 0x80000000u) ? (srt ^ 0x80000000u) : ~srt;
    return __uint_as_float(b);
}

__device__ __forceinline__ float area_of(float4 b) {
    return __fmul_rn(__fsub_rn(b.z, b.x), __fsub_rn(b.w, b.y));
}
// exact iou>0.45 decision, divide-free (strict > at midpoint; tie rounds to even=0.45f)
__device__ __forceinline__ bool sup_check(float4 a, float aarea, float4 c, float carea) {
    float ix1 = fmaxf(a.x, c.x), iy1 = fmaxf(a.y, c.y);
    float ix2 = fminf(a.z, c.z), iy2 = fminf(a.w, c.w);
    float inter = __fmul_rn(fmaxf(__fsub_rn(ix2, ix1), 0.f), fmaxf(__fsub_rn(iy2, iy1), 0.f));
    float uni = __fsub_rn(__fadd_rn(aarea, carea), inter);
    return (uni > 0.f) && ((double)inter > MIOU * (double)fmaxf(uni, 1e-12f));
}

// one bitonic compare-exchange pass with j<=32: partner is in-wave, via shfl
__device__ __forceinline__ ull cex_shfl(ull v, int j, bool asc, int lane) {
    ull pv = __shfl_xor(v, j);
    bool keepmin = (((lane & j) == 0) == asc);
    bool less = (v < pv);
    return (keepmin == less) ? v : pv;
}

// ---------------- Kernel A: fused decode + per-segment sort (512 boxes/block) ----------------
__global__ __launch_bounds__(512) void decode_sort_kernel(
    const float* __restrict__ y_pred, const float* __restrict__ box_tensor,
    float4* __restrict__ BX, ull* __restrict__ KS, ull* __restrict__ KS2)
{
    __shared__ float st[SEGSZ * 25];   // 51.2 KB
    __shared__ ull sk[SEGSZ];          // 4 KB
    int img = blockIdx.y, seg = blockIdx.x, tid = threadIdx.x;
    int b0 = seg * SEGSZ;
    int nval = NBOX - b0; nval = nval < 0 ? 0 : (nval > SEGSZ ? SEGSZ : nval);
    if (nval > 0) {
        const float* src = y_pred + ((size_t)img * NBOX + b0) * 25;
        int nf = nval * 25, nf4 = nf >> 2;
        const float4* src4 = (const float4*)src;
        float4* st4 = (float4*)st;
        for (int f = tid; f < nf4; f += 512) st4[f] = src4[f];
        for (int f = (nf4 << 2) + tid; f < nf; f += 512) st[f] = src[f];
    }
    __syncthreads();
    int i = b0 + tid;
    size_t o = (size_t)img * NPAD + i;
    ull v;
    if (tid < nval) {
        const float* yl = st + tid * 25;
        float best = yl[0]; int bi = 0;
        #pragma unroll
        for (int k = 1; k < NCLS; k++) { float x = yl[k]; if (x > best) { best = x; bi = k; } }
        float4 a = ((const float4*)box_tensor)[i];
        float t0 = yl[21], t1 = yl[22], t2 = yl[23], t3 = yl[24];
        float cx = __fadd_rn(__fmul_rn(__fmul_rn(t0, 0.1f), a.z), a.x);
        float cy = __fadd_rn(__fmul_rn(__fmul_rn(t1, 0.1f), a.w), a.y);
        float w  = __fmul_rn((float)exp((double)__fmul_rn(t2, 0.2f)), a.z);
        float h  = __fmul_rn((float)exp((double)__fmul_rn(t3, 0.2f)), a.w);
        float hw = __fmul_rn(0.5f, w), hh = __fmul_rn(0.5f, h);
        float xmin = fminf(fmaxf(__fsub_rn(cx, hw), 0.f), 1.f);
        float ymin = fminf(fmaxf(__fsub_rn(cy, hh), 0.f), 1.f);
        float xmax = fminf(fmaxf(__fadd_rn(cx, hw), 0.f), 1.f);
        float ymax = fminf(fmaxf(__fadd_rn(cy, hh), 0.f), 1.f);
        bool valid = (bi != 0) && (best > 0.01f);
        BX[o] = make_float4(xmin, ymin, xmax, ymax);
        uint hi = valid ? key_hi(best) : __float_as_uint(NEGV);
        v = ((ull)hi << 32) | ((uint)(i << 8)) | (uint)bi;
    } else {
        v = ((ull)__float_as_uint(NEGV) << 32) | ((uint)(i << 8));
    }
    // hybrid bitonic sort of 512 keys: j>=64 via LDS, j<=32 via shfl
    int lane = tid & 63;
    for (int k = 2; k <= SEGSZ; k <<= 1) {
        for (int j = k >> 1; j >= 64; j >>= 1) {
            sk[tid] = v; __syncthreads();
            ull pv = sk[tid ^ j];
            bool keepmin = (((tid & j) == 0) == ((tid & k) == 0));
            bool less = (v < pv);
            v = (keepmin == less) ? v : pv;
            __syncthreads();
        }
        int j0 = (k >> 1) < 32 ? (k >> 1) : 32;
        for (int j = j0; j >= 1; j >>= 1)
            v = cex_shfl(v, j, (tid & k) == 0, lane);
    }
    KS[(size_t)img * NPAD + b0 + tid] = v;                              // keys for phase-C fallback
    if (tid < OUTW) KS2[(size_t)img * (NSEG * OUTW) + seg * OUTW + tid] = v;
}

// ---------------- Kernel B: merge + batched greedy walk w/ precomputed in-batch masks ----------------
__global__ __launch_bounds__(512) void nms_kernel(
    const ull* __restrict__ KS2, const ull* __restrict__ KS,
    const float4* __restrict__ BX, float* __restrict__ out)
{
    __shared__ ull klist[MCAP];        // 8 KB
    __shared__ float4 cbox[WIN];       // 8 KB
    __shared__ ull scol[WIN];          // 4 KB  (bit i of scol[c]: batch-mate i suppresses c)
    __shared__ float4 accbox[100];
    __shared__ float  accarea[100];
    __shared__ ull pref[NSEG];

    int img = blockIdx.x, tid = threadIdx.x;
    int wid = tid >> 6, lane = tid & 63;
    const ull* ks2i = KS2 + (size_t)img * (NSEG * OUTW);
    const float4* BXg = BX + (size_t)img * NPAD;

    // stage 44 sorted prefixes of 23 into registers; e = wid*128 + r*64 + lane
    ull v[2];
    #pragma unroll
    for (int r = 0; r < 2; r++) {
        int e = (wid << 7) + (r << 6) + lane;
        v[r] = (e < NWALK) ? ks2i[(e / PFXS) * OUTW + (e % PFXS)] : ~0ull;
    }
    if (tid < NSEG) pref[tid] = ks2i[tid * OUTW + PFXS];

    // hybrid bitonic sort 1024 ascending: LDS (j>=128), reg (j=64), shfl (j<=32)
    for (int k = 2; k <= MCAP; k <<= 1) {
        if ((k >> 1) >= 128) {
            #pragma unroll
            for (int r = 0; r < 2; r++) klist[(wid << 7) + (r << 6) + lane] = v[r];
            for (int j = k >> 1; j >= 128; j >>= 1) {
                __syncthreads();
                int t = tid;
                int i = ((t & ~(j - 1)) << 1) | (t & (j - 1));
                int l = i | j;
                ull a = klist[i], b = klist[l];
                if ((a > b) == ((i & k) == 0)) { klist[i] = b; klist[l] = a; }
            }
            __syncthreads();
            #pragma unroll
            for (int r = 0; r < 2; r++) v[r] = klist[(wid << 7) + (r << 6) + lane];
        }
        if ((k >> 1) >= 64) {              // j = 64: same-lane register CE
            int e = (wid << 7) + lane;
            bool asc = ((e & k) == 0);
            ull a = v[0], b = v[1];
            if ((a > b) == asc) { v[0] = b; v[1] = a; }
        }
        int j0 = (k >> 1) < 32 ? (k >> 1) : 32;
        for (int j = j0; j >= 1; j >>= 1) {
            #pragma unroll
            for (int r = 0; r < 2; r++) {
                int e = (wid << 7) + (r << 6) + lane;
                v[r] = cex_shfl(v[r], j, (e & k) == 0, lane);
            }
        }
    }
    #pragma unroll
    for (int r = 0; r < 2; r++) klist[(wid << 7) + (r << 6) + lane] = v[r];
    __syncthreads();

    // window prep: wave w handles batch w (WIN/64 = 8 batches, one per wave)
    {
        int c = (wid << 6) + lane;
        ull k = klist[c];
        float4 bx = BXg[((uint)k) >> 8];
        cbox[c] = bx;
        float myar = area_of(bx);
        ull col = 0;
        #pragma unroll 4
        for (int i = 0; i < 64; i++) {
            float4 ib = cbox[(wid << 6) + i];
            bool s = (i < lane) && sup_check(ib, area_of(ib), bx, myar);
            col |= ((ull)s) << i;
        }
        scol[c] = col;
    }
    __syncthreads();

    if (tid >= 64) return;             // resolve: wave 0 only
    float* orow = out + (size_t)img * 600;
    const ull* ksg = KS + (size_t)img * NPAD;

    ull cutk = ~0ull;
    for (int s = 0; s < NSEG; s++) { ull x = pref[s]; if (x < cutk) cutk = x; }

    int A = 0, stop = 0, done = 0;
    int acc0 = 0, acc1 = 0;            // accepted window positions per lane

    for (int base = 0; base < WIN && !stop; base += 64) {
        int c = base + lane;
        ull kk = klist[c];
        float4 bb = cbox[c];
        float ca = area_of(bb);
        ull mycol = scol[c];
        bool valid = !(kk >> 63) && (kk < cutk);
        ull vmask = __ballot(valid);
        bool alive = valid;
        for (int a = 0; a < A; a++)
            alive = alive & !sup_check(accbox[a], accarea[a], bb, ca);
        ull m = __ballot(alive);
        while (m && A < 100) {
            int i = __ffsll(m) - 1;
            if (lane == i) { accbox[A] = bb; accarea[A] = ca; }
            if (lane == (A & 63)) { if (A < 64) acc0 = base + i; else acc1 = base + i; }
            A++;
            m &= ~(1ull << i);
            m &= __ballot(!((mycol >> i) & 1ull));
        }
        if (A >= 100) { stop = 1; done = 1; }
        else if (vmask != ~0ull) {
            stop = 1;
            int fi = __ffsll(~vmask) - 1;
            ull fk = __shfl(kk, fi);
            done = (fk >= cutk) ? (int)(cutk >> 63) : 1;
        }
        __builtin_amdgcn_wave_barrier();
    }

    // batch-write window outputs (lane-parallel)
    int accW = A;
    if (lane < accW) {
        ull k = klist[acc0]; float4 b = cbox[acc0];
        float* o = orow + lane * 6;
        o[0] = (float)((uint)k & 0xffu); o[1] = key_score((uint)(k >> 32));
        o[2] = b.x; o[3] = b.y; o[4] = b.z; o[5] = b.w;
    }
    if (64 + lane < accW) {
        ull k = klist[acc1]; float4 b = cbox[acc1];
        float* o = orow + (64 + lane) * 6;
        o[0] = (float)((uint)k & 0xffu); o[1] = key_score((uint)(k >> 32));
        o[2] = b.x; o[3] = b.y; o[4] = b.z; o[5] = b.w;
    }

    // phase B: staged keys beyond the window (expected dead: walk depth ~200 < WIN)
    if (!stop) {
        for (int base = WIN; base < MCAP && !stop; base += 64) {
            int pos = base + lane;
            ull kk = klist[pos];
            bool valid = !(kk >> 63) && (kk < cutk);
            ull vmask = __ballot(valid);
            float4 bb = BXg[((uint)kk) >> 8];
            float ca = area_of(bb);
            bool alive = valid;
            for (int a = 0; a < A; a++)
                alive = alive & !sup_check(accbox[a], accarea[a], bb, ca);
            ull cand = __ballot(alive);
            while (cand && A < 100) {
                int i = __ffsll(cand) - 1;
                float4 ib = make_float4(__shfl(bb.x, i), __shfl(bb.y, i),
                                        __shfl(bb.z, i), __shfl(bb.w, i));
                float ia = __shfl(ca, i);
                ull row = __ballot(sup_check(ib, ia, bb, ca));
                if (lane == i) {
                    accbox[A] = bb; accarea[A] = ca;
                    float* o = orow + A * 6;
                    o[0] = (float)((uint)kk & 0xffu); o[1] = key_score((uint)(kk >> 32));
                    o[2] = bb.x; o[3] = bb.y; o[4] = bb.z; o[5] = bb.w;
                }
                A++;
                cand &= ~(1ull << i);
                cand &= ~row;
            }
            if (A >= 100) { stop = 1; done = 1; }
            else if (vmask != ~0ull) {
                stop = 1;
                int fi = __ffsll(~vmask) - 1;
                ull fk = __shfl(kk, fi);
                done = (fk >= cutk) ? (int)(cutk >> 63) : 1;
            }
            __builtin_amdgcn_wave_barrier();
        }
        if (!stop) done = (int)(cutk >> 63);
    }

    // phase C fallback (expected dead): ordered pops over full key array from cutk
    if (!done && A < 100) {
        ull nextk = cutk;
        while (A < 100) {
            ull best = ~0ull;
            for (int e = lane; e < NPAD; e += 64) {
                ull kk2 = ksg[e];
                if (kk2 >= nextk && kk2 < best) best = kk2;
            }
            #pragma unroll
            for (int off = 32; off; off >>= 1) {
                ull oo = __shfl_xor(best, off);
                if (oo < best) best = oo;
            }
            if (best >> 63) break;
            uint bhi = (uint)(best >> 32), blo = (uint)best;
            float4 cb = BXg[blo >> 8];
            float ca2 = area_of(cb);
            bool sup2 = false;
            #pragma unroll
            for (int t = 0; t < 2; t++) {
                int slot = lane + 64 * t;
                if (slot < A && sup_check(accbox[slot], accarea[slot], cb, ca2)) sup2 = true;
            }
            if (__ballot(sup2) == 0ull) {
                if (lane == 0) {
                    accbox[A] = cb; accarea[A] = ca2;
                    float* o = orow + A * 6;
                    o[0] = (float)(blo & 0xffu); o[1] = key_score(bhi);
                    o[2] = cb.x; o[3] = cb.y; o[4] = cb.z; o[5] = cb.w;
                }
                A++;
            }
            nextk = best + 1;
            __builtin_amdgcn_wave_barrier();
        }
    }

    for (int r = lane; r < (100 - A) * 6; r += 64) orow[A * 6 + r] = 0.f;
}

extern "C" void kernel_launch(void* const* d_in, const int* in_sizes, int n_in,
                              void* d_out, int out_size, void* d_ws, size_t ws_size,
                              hipStream_t stream)
{
    const float* y_pred     = (const float*)d_in[0];
    const float* box_tensor = (const float*)d_in[1];
    float* out = (float*)d_out;

    size_t stride = (size_t)BATCH * NPAD;
    ull*    KS  = (ull*)d_ws;                       // 5.77 MB
    float4* BX  = (float4*)(KS + stride);           // 11.53 MB
    ull*    KS2 = (ull*)(BX + stride);              // 0.27 MB

    decode_sort_kernel<<<dim3(NSEG, BATCH), 512, 0, stream>>>(y_pred, box_tensor, BX, KS, KS2);
    nms_kernel<<<BATCH, 512, 0, stream>>>(KS2, KS, BX, out);
}

// Round 8
// 139.634 us; speedup vs baseline: 1.5540x; 1.0278x over previous
//
#include <hip/hip_runtime.h>
#include <math.h>

typedef unsigned long long ull;
typedef unsigned int uint;

#define NBOX 21840
#define SEGSZ 512
#define NSEG 44
#define NPAD (NSEG*SEGSZ)     // 22528
#define PFXS 23               // staged per segment
#define OUTW 24               // 23 staged + 1 pref key
#define NWALK (NSEG*PFXS)     // 1012
#define MCAP 1024
#define WIN 512               // fast window with precomputed within-batch masks
#define BATCH 32
#define NCLS 21
#define NEGV -1e30f
// midpoint(0.45f, nextafterf(0.45f)) = 15099494.5 * 2^-25, exactly representable.
// RN(inter/u) > 0.45f  <=>  (double)inter > MIOU * (double)u   (u > 0)
#define MIOU (15099494.5/33554432.0)

// ---- sortable key: ascending u64 == (score desc, idx asc); lo = (idx<<8)|cls ----
__device__ __forceinline__ uint key_hi(float s) {
    uint b = __float_as_uint(s);
    uint m = (uint)((int)b >> 31) | 0x80000000u;
    return ~(b ^ m);                       // valid (s>0.01>0) => hi < 0x80000000
}
__device__ __forceinline__ float key_score(uint hi) {
    uint srt = ~hi;
    uint b = (srt & 0x80000000u) ? (srt ^ 0x80000000u) : ~srt;
    return __uint_as_float(b);
}

__device__ __forceinline__ float area_of(float4 b) {
    return __fmul_rn(__fsub_rn(b.z, b.x), __fsub_rn(b.w, b.y));
}
// exact iou>0.45 decision, divide-free (strict > at midpoint; tie rounds to even=0.45f)
__device__ __forceinline__ bool sup_check(float4 a, float aarea, float4 c, float carea) {
    float ix1 = fmaxf(a.x, c.x), iy1 = fmaxf(a.y, c.y);
    float ix2 = fminf(a.z, c.z), iy2 = fminf(a.w, c.w);
    float inter = __fmul_rn(fmaxf(__fsub_rn(ix2, ix1), 0.f), fmaxf(__fsub_rn(iy2, iy1), 0.f));
    float uni = __fsub_rn(__fadd_rn(aarea, carea), inter);
    return (uni > 0.f) && ((double)inter > MIOU * (double)fmaxf(uni, 1e-12f));
}

// one bitonic compare-exchange pass with j<=32: partner is in-wave, via shfl
__device__ __forceinline__ ull cex_shfl(ull v, int j, bool asc, int lane) {
    ull pv = __shfl_xor(v, j);
    bool keepmin = (((lane & j) == 0) == asc);
    bool less = (v < pv);
    return (keepmin == less) ? v : pv;
}

// ---------------- Kernel A: decode + hierarchical top-24 selection ----------------
__global__ __launch_bounds__(512) void decode_sort_kernel(
    const float* __restrict__ y_pred, const float* __restrict__ box_tensor,
    float4* __restrict__ BX, ull* __restrict__ KS, ull* __restrict__ KS2)
{
    __shared__ float st[SEGSZ * 25];   // 51.2 KB
    __shared__ ull mbuf[8 * 24];       // 1.5 KB: per-wave top-24
    int img = blockIdx.y, seg = blockIdx.x, tid = threadIdx.x;
    int wid = tid >> 6, lane = tid & 63;
    int b0 = seg * SEGSZ;
    int nval = NBOX - b0; nval = nval < 0 ? 0 : (nval > SEGSZ ? SEGSZ : nval);
    if (nval > 0) {
        const float* src = y_pred + ((size_t)img * NBOX + b0) * 25;
        int nf = nval * 25, nf4 = nf >> 2;
        const float4* src4 = (const float4*)src;
        float4* st4 = (float4*)st;
        for (int f = tid; f < nf4; f += 512) st4[f] = src4[f];
        for (int f = (nf4 << 2) + tid; f < nf; f += 512) st[f] = src[f];
    }
    __syncthreads();
    int i = b0 + tid;
    size_t o = (size_t)img * NPAD + i;
    ull v;
    if (tid < nval) {
        const float* yl = st + tid * 25;
        float best = yl[0]; int bi = 0;
        #pragma unroll
        for (int k = 1; k < NCLS; k++) { float x = yl[k]; if (x > best) { best = x; bi = k; } }
        float4 a = ((const float4*)box_tensor)[i];
        float t0 = yl[21], t1 = yl[22], t2 = yl[23], t3 = yl[24];
        float cx = __fadd_rn(__fmul_rn(__fmul_rn(t0, 0.1f), a.z), a.x);
        float cy = __fadd_rn(__fmul_rn(__fmul_rn(t1, 0.1f), a.w), a.y);
        float w  = __fmul_rn((float)exp((double)__fmul_rn(t2, 0.2f)), a.z);
        float h  = __fmul_rn((float)exp((double)__fmul_rn(t3, 0.2f)), a.w);
        float hw = __fmul_rn(0.5f, w), hh = __fmul_rn(0.5f, h);
        float xmin = fminf(fmaxf(__fsub_rn(cx, hw), 0.f), 1.f);
        float ymin = fminf(fmaxf(__fsub_rn(cy, hh), 0.f), 1.f);
        float xmax = fminf(fmaxf(__fadd_rn(cx, hw), 0.f), 1.f);
        float ymax = fminf(fmaxf(__fadd_rn(cy, hh), 0.f), 1.f);
        bool valid = (bi != 0) && (best > 0.01f);
        BX[o] = make_float4(xmin, ymin, xmax, ymax);
        uint hi = valid ? key_hi(best) : __float_as_uint(NEGV);
        v = ((ull)hi << 32) | ((uint)(i << 8)) | (uint)bi;
    } else {
        v = ((ull)__float_as_uint(NEGV) << 32) | ((uint)(i << 8));
    }
    KS[o] = v;                         // raw keys: phase-C fallback is order-agnostic

    // wave-local full sort of 64 keys (shfl-only, zero barriers); lane i -> i-th smallest
    for (int k = 2; k <= 64; k <<= 1) {
        bool asc = (k == 64) || ((lane & k) == 0);
        for (int j = k >> 1; j >= 1; j >>= 1)
            v = cex_shfl(v, j, asc, lane);
    }
    if (lane < 24) mbuf[wid * 24 + lane] = v;
    __syncthreads();

    if (wid != 0) return;              // waves 1-7 done (their global writes drain)

    // wave 0: in-register 256-sort of the 192 wave-top-24s (padded), emit top-24
    ull m[4];
    #pragma unroll
    for (int r = 0; r < 4; r++) {
        int e = (r << 6) + lane;
        m[r] = (e < 192) ? mbuf[e] : ~0ull;
    }
    for (int k = 2; k <= 256; k <<= 1) {
        #pragma unroll
        for (int jr = 2; jr >= 1; jr >>= 1) {      // j = 128, 64: same-lane register CE
            int j = jr << 6;
            if ((k >> 1) >= j) {
                #pragma unroll
                for (int r = 0; r < 4; r++) {
                    if ((r & jr) == 0) {
                        int rh = r | jr;
                        int e = (r << 6) + lane;
                        bool asc = ((e & k) == 0) || (k == 256);
                        ull a = m[r], b = m[rh];
                        if ((a > b) == asc) { m[r] = b; m[rh] = a; }
                    }
                }
            }
        }
        int j0 = (k >> 1) < 32 ? (k >> 1) : 32;
        for (int j = j0; j >= 1; j >>= 1) {
            #pragma unroll
            for (int r = 0; r < 4; r++) {
                int e = (r << 6) + lane;
                bool asc = ((e & k) == 0) || (k == 256);
                m[r] = cex_shfl(m[r], j, asc, lane);
            }
        }
    }
    if (lane < OUTW) KS2[(size_t)img * (NSEG * OUTW) + seg * OUTW + lane] = m[0];
}

// ---------------- Kernel B: merge + batched greedy walk w/ precomputed in-batch masks ----------------
__global__ __launch_bounds__(512) void nms_kernel(
    const ull* __restrict__ KS2, const ull* __restrict__ KS,
    const float4* __restrict__ BX, float* __restrict__ out)
{
    __shared__ ull klist[MCAP];        // 8 KB
    __shared__ float4 cbox[WIN];       // 8 KB
    __shared__ ull scol[WIN];          // 4 KB  (bit i of scol[c]: batch-mate i suppresses c)
    __shared__ float4 accbox[100];
    __shared__ float  accarea[100];
    __shared__ ull pref[NSEG];

    int img = blockIdx.x, tid = threadIdx.x;
    int wid = tid >> 6, lane = tid & 63;
    const ull* ks2i = KS2 + (size_t)img * (NSEG * OUTW);
    const float4* BXg = BX + (size_t)img * NPAD;

    // stage 44 sorted prefixes of 23 into registers; e = wid*128 + r*64 + lane
    ull v[2];
    #pragma unroll
    for (int r = 0; r < 2; r++) {
        int e = (wid << 7) + (r << 6) + lane;
        v[r] = (e < NWALK) ? ks2i[(e / PFXS) * OUTW + (e % PFXS)] : ~0ull;
    }
    if (tid < NSEG) pref[tid] = ks2i[tid * OUTW + PFXS];

    // hybrid bitonic sort 1024 ascending: LDS (j>=128), reg (j=64), shfl (j<=32)
    for (int k = 2; k <= MCAP; k <<= 1) {
        if ((k >> 1) >= 128) {
            #pragma unroll
            for (int r = 0; r < 2; r++) klist[(wid << 7) + (r << 6) + lane] = v[r];
            for (int j = k >> 1; j >= 128; j >>= 1) {
                __syncthreads();
                int t = tid;
                int i = ((t & ~(j - 1)) << 1) | (t & (j - 1));
                int l = i | j;
                ull a = klist[i], b = klist[l];
                if ((a > b) == ((i & k) == 0)) { klist[i] = b; klist[l] = a; }
            }
            __syncthreads();
            #pragma unroll
            for (int r = 0; r < 2; r++) v[r] = klist[(wid << 7) + (r << 6) + lane];
        }
        if ((k >> 1) >= 64) {              // j = 64: same-lane register CE
            int e = (wid << 7) + lane;
            bool asc = ((e & k) == 0);
            ull a = v[0], b = v[1];
            if ((a > b) == asc) { v[0] = b; v[1] = a; }
        }
        int j0 = (k >> 1) < 32 ? (k >> 1) : 32;
        for (int j = j0; j >= 1; j >>= 1) {
            #pragma unroll
            for (int r = 0; r < 2; r++) {
                int e = (wid << 7) + (r << 6) + lane;
                v[r] = cex_shfl(v[r], j, (e & k) == 0, lane);
            }
        }
    }
    #pragma unroll
    for (int r = 0; r < 2; r++) klist[(wid << 7) + (r << 6) + lane] = v[r];
    __syncthreads();

    // window prep: wave w handles batch w (WIN/64 = 8 batches, one per wave)
    {
        int c = (wid << 6) + lane;
        ull k = klist[c];
        float4 bx = BXg[((uint)k) >> 8];
        cbox[c] = bx;
        float myar = area_of(bx);
        ull col = 0;
        #pragma unroll 4
        for (int i = 0; i < 64; i++) {
            float4 ib = cbox[(wid << 6) + i];
            bool s = (i < lane) && sup_check(ib, area_of(ib), bx, myar);
            col |= ((ull)s) << i;
        }
        scol[c] = col;
    }
    __syncthreads();

    if (tid >= 64) return;             // resolve: wave 0 only
    float* orow = out + (size_t)img * 600;
    const ull* ksg = KS + (size_t)img * NPAD;

    ull cutk = ~0ull;
    for (int s = 0; s < NSEG; s++) { ull x = pref[s]; if (x < cutk) cutk = x; }

    int A = 0, stop = 0, done = 0;
    int acc0 = 0, acc1 = 0;            // accepted window positions per lane

    for (int base = 0; base < WIN && !stop; base += 64) {
        int c = base + lane;
        ull kk = klist[c];
        float4 bb = cbox[c];
        float ca = area_of(bb);
        ull mycol = scol[c];
        bool valid = !(kk >> 63) && (kk < cutk);
        ull vmask = __ballot(valid);
        bool alive = valid;
        for (int a = 0; a < A; a++)
            alive = alive & !sup_check(accbox[a], accarea[a], bb, ca);
        ull m = __ballot(alive);
        while (m && A < 100) {
            int i = __ffsll(m) - 1;
            if (lane == i) { accbox[A] = bb; accarea[A] = ca; }
            if (lane == (A & 63)) { if (A < 64) acc0 = base + i; else acc1 = base + i; }
            A++;
            m &= ~(1ull << i);
            m &= __ballot(!((mycol >> i) & 1ull));
        }
        if (A >= 100) { stop = 1; done = 1; }
        else if (vmask != ~0ull) {
            stop = 1;
            int fi = __ffsll(~vmask) - 1;
            ull fk = __shfl(kk, fi);
            done = (fk >= cutk) ? (int)(cutk >> 63) : 1;
        }
        __builtin_amdgcn_wave_barrier();
    }

    // batch-write window outputs (lane-parallel)
    int accW = A;
    if (lane < accW) {
        ull k = klist[acc0]; float4 b = cbox[acc0];
        float* o = orow + lane * 6;
        o[0] = (float)((uint)k & 0xffu); o[1] = key_score((uint)(k >> 32));
        o[2] = b.x; o[3] = b.y; o[4] = b.z; o[5] = b.w;
    }
    if (64 + lane < accW) {
        ull k = klist[acc1]; float4 b = cbox[acc1];
        float* o = orow + (64 + lane) * 6;
        o[0] = (float)((uint)k & 0xffu); o[1] = key_score((uint)(k >> 32));
        o[2] = b.x; o[3] = b.y; o[4] = b.z; o[5] = b.w;
    }

    // phase B: staged keys beyond the window (expected dead: walk depth ~200 < WIN)
    if (!stop) {
        for (int base = WIN; base < MCAP && !stop; base += 64) {
            int pos = base + lane;
            ull kk = klist[pos];
            bool valid = !(kk >> 63) && (kk < cutk);
            ull vmask = __ballot(valid);
            float4 bb = BXg[((uint)kk) >> 8];
            float ca = area_of(bb);
            bool alive = valid;
            for (int a = 0; a < A; a++)
                alive = alive & !sup_check(accbox[a], accarea[a], bb, ca);
            ull cand = __ballot(alive);
            while (cand && A < 100) {
                int i = __ffsll(cand) - 1;
                float4 ib = make_float4(__shfl(bb.x, i), __shfl(bb.y, i),
                                        __shfl(bb.z, i), __shfl(bb.w, i));
                float ia = __shfl(ca, i);
                ull row = __ballot(sup_check(ib, ia, bb, ca));
                if (lane == i) {
                    accbox[A] = bb; accarea[A] = ca;
                    float* o = orow + A * 6;
                    o[0] = (float)((uint)kk & 0xffu); o[1] = key_score((uint)(kk >> 32));
                    o[2] = bb.x; o[3] = bb.y; o[4] = bb.z; o[5] = bb.w;
                }
                A++;
                cand &= ~(1ull << i);
                cand &= ~row;
            }
            if (A >= 100) { stop = 1; done = 1; }
            else if (vmask != ~0ull) {
                stop = 1;
                int fi = __ffsll(~vmask) - 1;
                ull fk = __shfl(kk, fi);
                done = (fk >= cutk) ? (int)(cutk >> 63) : 1;
            }
            __builtin_amdgcn_wave_barrier();
        }
        if (!stop) done = (int)(cutk >> 63);
    }

    // phase C fallback (expected dead): ordered pops over full (unsorted) key array from cutk
    if (!done && A < 100) {
        ull nextk = cutk;
        while (A < 100) {
            ull best = ~0ull;
            for (int e = lane; e < NPAD; e += 64) {
                ull kk2 = ksg[e];
                if (kk2 >= nextk && kk2 < best) best = kk2;
            }
            #pragma unroll
            for (int off = 32; off; off >>= 1) {
                ull oo = __shfl_xor(best, off);
                if (oo < best) best = oo;
            }
            if (best >> 63) break;
            uint bhi = (uint)(best >> 32), blo = (uint)best;
            float4 cb = BXg[blo >> 8];
            float ca2 = area_of(cb);
            bool sup2 = false;
            #pragma unroll
            for (int t = 0; t < 2; t++) {
                int slot = lane + 64 * t;
                if (slot < A && sup_check(accbox[slot], accarea[slot], cb, ca2)) sup2 = true;
            }
            if (__ballot(sup2) == 0ull) {
                if (lane == 0) {
                    accbox[A] = cb; accarea[A] = ca2;
                    float* o = orow + A * 6;
                    o[0] = (float)(blo & 0xffu); o[1] = key_score(bhi);
                    o[2] = cb.x; o[3] = cb.y; o[4] = cb.z; o[5] = cb.w;
                }
                A++;
            }
            nextk = best + 1;
            __builtin_amdgcn_wave_barrier();
        }
    }

    for (int r = lane; r < (100 - A) * 6; r += 64) orow[A * 6 + r] = 0.f;
}

extern "C" void kernel_launch(void* const* d_in, const int* in_sizes, int n_in,
                              void* d_out, int out_size, void* d_ws, size_t ws_size,
                              hipStream_t stream)
{
    const float* y_pred     = (const float*)d_in[0];
    const float* box_tensor = (const float*)d_in[1];
    float* out = (float*)d_out;

    size_t stride = (size_t)BATCH * NPAD;
    ull*    KS  = (ull*)d_ws;                       // 5.77 MB (raw keys, phase-C only)
    float4* BX  = (float4*)(KS + stride);           // 11.53 MB
    ull*    KS2 = (ull*)(BX + stride);              // 0.27 MB

    decode_sort_kernel<<<dim3(NSEG, BATCH), 512, 0, stream>>>(y_pred, box_tensor, BX, KS, KS2);
    nms_kernel<<<BATCH, 512, 0, stream>>>(KS2, KS, BX, out);
}